// Round 4
// baseline (201.207 us; speedup 1.0000x reference)
//
#include <hip/hip_runtime.h>

// out[m,u] = x2[m] + w2[u] - 2 * sum_k x[m,k] * w[k,u]
// x[32768, 128] f32, w[128, 1024] f32, out[32768, 1024] f32
#define M_TOT 32768
#define K_DIM 128
#define U_TOT 1024

#define GBM 64      // rows per subtile
#define GBN 64      // cols per block
#define NMS 8       // subtiles per block -> block covers 512 rows x 64 cols

typedef short s16x8 __attribute__((ext_vector_type(8)));    // 8 bf16 (4 VGPRs)
typedef float f32x16 __attribute__((ext_vector_type(16)));  // 32x32 MFMA acc

// round-to-nearest-even fp32 -> bf16 (as ushort)
__device__ inline unsigned int f2bf(float f) {
    union { float f; unsigned int u; } v; v.f = f;
    return (v.u + 0x7FFFu + ((v.u >> 16) & 1u)) >> 16;
}

// prep: x -> bf16 row-major xb + x2 (blocks 0..4095, 8 rows each);
//       w -> w^T bf16 wt + w2 (blocks 4096..4351, 4 u each).  [unchanged from r3]
__global__ __launch_bounds__(256) void prep_kernel(
    const float* __restrict__ x, const float* __restrict__ w,
    unsigned int* __restrict__ xb, unsigned int* __restrict__ wt,
    float* __restrict__ x2, float* __restrict__ w2)
{
    const int lane = threadIdx.x & 63;
    const int lc = lane & 31;
    if (blockIdx.x < 4096) {
        const int wv = threadIdx.x >> 6;
        const int row = (blockIdx.x << 3) + (wv << 1) + (lane >> 5);
        const float4 v = ((const float4*)(x + (size_t)row * K_DIM))[lc];
        float s = v.x * v.x + v.y * v.y + v.z * v.z + v.w * v.w;
        #pragma unroll
        for (int off = 16; off; off >>= 1) s += __shfl_xor(s, off);
        uint2 pk;
        pk.x = f2bf(v.x) | (f2bf(v.y) << 16);
        pk.y = f2bf(v.z) | (f2bf(v.w) << 16);
        ((uint2*)xb)[(size_t)row * 32 + lc] = pk;   // k = lc*4 .. lc*4+3
        if (lc == 0) x2[row] = s;
    } else {
        const int u = ((blockIdx.x - 4096) << 2) + (threadIdx.x >> 6);
        const float a = w[(size_t)(2 * lane) * U_TOT + u];
        const float b = w[(size_t)(2 * lane + 1) * U_TOT + u];
        float s = a * a + b * b;
        #pragma unroll
        for (int off = 32; off; off >>= 1) s += __shfl_xor(s, off);
        wt[u * 64 + lane] = f2bf(a) | (f2bf(b) << 16);
        if (lane == 0) w2[u] = s;
    }
}

// GEMM v4: ZERO LDS, ZERO barriers — pure register streaming.
// xb tiles and wt are L2-resident by the XCD mapping (Common-mistake #7:
// don't LDS-stage cache-fit data). 1024 blocks x 256 thr (4 waves, 2x2).
// Wave (wr,wc): rows wr*32 of each 64-row subtile, cols wc*32 of the 64-col stripe.
// Per wave: an A-fragment group (8x global 16B/lane) reads a contiguous 8KB
// block (32 rows x 256B) with every byte exactly once -> aggregate-coalesced.
__global__ __launch_bounds__(256, 4) void gemm_kernel(
    const unsigned short* __restrict__ xb, const unsigned short* __restrict__ wt,
    const float* __restrict__ x2, const float* __restrict__ w2,
    float* __restrict__ out)
{
    const int tid = threadIdx.x;
    const int wv = tid >> 6;
    const int lane = tid & 63;
    const int lc = lane & 31;
    const int hi = lane >> 5;
    const int wr = wv >> 1;                    // 0..1 row group
    const int wc = wv & 1;                     // 0..1 col group

    // XCD mapping (b%8 = XCD): XCD j owns rows 4096j..4096(j+1); its 16
    // consecutive blocks per row-group share a 512-row xb band via its L2.
    const int b = blockIdx.x;
    const int t = b >> 3;
    const int ut = t & 15;                     // 0..15
    const int msb = (b & 7) * 8 + (t >> 4);    // 0..63
    const int u0 = ut * GBN;
    const int mbase = msb * (GBM * NMS);

    // B fragments straight from global (wt = 256KB, L2-resident everywhere).
    // lane holds B[k][col]: col = wc*32+lc, k = st*16 + hi*8 + 0..7
    const unsigned short* wp = wt + ((size_t)(u0 + wc * 32 + lc) << 7) + (hi << 3);
    s16x8 bfrag[8];
    #pragma unroll
    for (int st = 0; st < 8; ++st)
        bfrag[st] = *(const s16x8*)(wp + (st << 4));

    const float w2v = w2[u0 + wc * 32 + lc];

    #pragma unroll
    for (int ms = 0; ms < NMS; ++ms) {
        const int mb = mbase + ms * GBM + wr * 32;
        const unsigned short* ap = xb + ((size_t)(mb + lc) << 7) + (hi << 3);
        const float x2row = x2[mb + lc];

        // A fragments: lane holds A[row=mb+lc][k = st*16 + hi*8 + 0..7]
        s16x8 af[8];
        #pragma unroll
        for (int st = 0; st < 8; ++st)
            af[st] = *(const s16x8*)(ap + (st << 4));

        f32x16 acc = {};
        #pragma unroll
        for (int st = 0; st < 8; ++st)
            acc = __builtin_amdgcn_mfma_f32_32x32x16_bf16(af[st], bfrag[st], acc, 0, 0, 0);

        // C/D 32x32: col=lane&31, row=(r&3)+8*(r>>2)+4*hi (m74/m101-verified;
        // identical epilogue to the r3-passed kernel). Each store: 2x128B lines.
        float* op = out + (size_t)mb * U_TOT + u0 + wc * 32 + lc;
        #pragma unroll
        for (int r = 0; r < 16; ++r) {
            const int tt = (r & 3) + ((r >> 2) << 3);
            const float xs = __shfl(x2row, tt + (hi << 2) + (lane & 32));
            op[(size_t)(tt + (hi << 2)) * U_TOT] = xs + w2v - 2.0f * acc[r];
        }
    }
}

// Fallback (no workspace): correct fp32 path, used only if ws_size is too small.
__global__ __launch_bounds__(256) void fallback_kernel(
    const float* __restrict__ x, const float* __restrict__ w,
    float* __restrict__ out)
{
    __shared__ float xrow[K_DIM];
    const int m = blockIdx.x;
    const int tid = threadIdx.x;
    if (tid < K_DIM) xrow[tid] = x[(size_t)m * K_DIM + tid];
    __syncthreads();
    float x2 = 0.f;
    #pragma unroll
    for (int k = 0; k < K_DIM; ++k) x2 += xrow[k] * xrow[k];
    #pragma unroll
    for (int uu = 0; uu < 4; ++uu) {
        const int u = uu * 256 + tid;
        float dot = 0.f, w2 = 0.f;
        for (int k = 0; k < K_DIM; ++k) {
            const float wv = w[(size_t)k * U_TOT + u];
            dot += xrow[k] * wv;
            w2 += wv * wv;
        }
        out[(size_t)m * U_TOT + u] = x2 + w2 - 2.0f * dot;
    }
}

extern "C" void kernel_launch(void* const* d_in, const int* in_sizes, int n_in,
                              void* d_out, int out_size, void* d_ws, size_t ws_size,
                              hipStream_t stream) {
    const float* x = (const float*)d_in[0];
    const float* w = (const float*)d_in[1];
    float* out = (float*)d_out;

    // ws layout: xb bf16[32768*128] | wt bf16[1024*128] | x2 f32[32768] | w2 f32[1024]
    const size_t need = (size_t)M_TOT * K_DIM * 2 + (size_t)U_TOT * K_DIM * 2
                      + (size_t)M_TOT * 4 + (size_t)U_TOT * 4;
    if (ws_size < need) {
        fallback_kernel<<<M_TOT, 256, 0, stream>>>(x, w, out);
        return;
    }

    unsigned short* xb = (unsigned short*)d_ws;
    unsigned short* wt = xb + (size_t)M_TOT * K_DIM;
    float* x2 = (float*)(wt + (size_t)U_TOT * K_DIM);
    float* w2 = x2 + M_TOT;

    prep_kernel<<<4096 + 256, 256, 0, stream>>>(x, w, (unsigned int*)xb,
                                                (unsigned int*)wt, x2, w2);
    gemm_kernel<<<(M_TOT / (GBM * NMS)) * (U_TOT / GBN), 256, 0, stream>>>(xb, wt, x2, w2, out);
}

// Round 5
// 152.147 us; speedup vs baseline: 1.3225x; 1.3225x over previous
//
#include <hip/hip_runtime.h>

// out[m,u] = x2[m] + w2[u] - 2 * sum_k x[m,k] * w[k,u]
// x[32768, 128] f32, w[128, 1024] f32, out[32768, 1024] f32
#define M_TOT 32768
#define K_DIM 128
#define U_TOT 1024

#define GBM 64      // rows per pipeline subtile
#define GBN 128     // cols per block
#define NMS 8       // subtiles per block -> block covers 512 rows x 128 cols

typedef short s16x8 __attribute__((ext_vector_type(8)));    // 8 bf16 (4 VGPRs)
typedef float f32x16 __attribute__((ext_vector_type(16)));  // 32x32 MFMA acc

// round-to-nearest-even fp32 -> bf16 (as ushort)
__device__ inline unsigned int f2bf(float f) {
    union { float f; unsigned int u; } v; v.f = f;
    return (v.u + 0x7FFFu + ((v.u >> 16) & 1u)) >> 16;
}

// async global->LDS, 16B per lane; LDS dest = wave-uniform base + lane*16
__device__ inline void async_load16(const void* g, void* l) {
    __builtin_amdgcn_global_load_lds((const __attribute__((address_space(1))) void*)g,
                                     (__attribute__((address_space(3))) void*)l,
                                     16, 0, 0);
}

// prep: x -> bf16 row-major xb + x2 (blocks 0..4095, 8 rows each);
//       w -> w^T bf16 wt + w2 (blocks 4096..4351, 4 u each).  [r3/r4-verified]
__global__ __launch_bounds__(256) void prep_kernel(
    const float* __restrict__ x, const float* __restrict__ w,
    unsigned int* __restrict__ xb, unsigned int* __restrict__ wt,
    float* __restrict__ x2, float* __restrict__ w2)
{
    const int lane = threadIdx.x & 63;
    const int lc = lane & 31;
    if (blockIdx.x < 4096) {
        const int wv = threadIdx.x >> 6;
        const int row = (blockIdx.x << 3) + (wv << 1) + (lane >> 5);
        const float4 v = ((const float4*)(x + (size_t)row * K_DIM))[lc];
        float s = v.x * v.x + v.y * v.y + v.z * v.z + v.w * v.w;
        #pragma unroll
        for (int off = 16; off; off >>= 1) s += __shfl_xor(s, off);
        uint2 pk;
        pk.x = f2bf(v.x) | (f2bf(v.y) << 16);
        pk.y = f2bf(v.z) | (f2bf(v.w) << 16);
        ((uint2*)xb)[(size_t)row * 32 + lc] = pk;   // k = lc*4 .. lc*4+3
        if (lc == 0) x2[row] = s;
    } else {
        const int u = ((blockIdx.x - 4096) << 2) + (threadIdx.x >> 6);
        const float a = w[(size_t)(2 * lane) * U_TOT + u];
        const float b = w[(size_t)(2 * lane + 1) * U_TOT + u];
        float s = a * a + b * b;
        #pragma unroll
        for (int off = 32; off; off >>= 1) s += __shfl_xor(s, off);
        wt[u * 64 + lane] = f2bf(a) | (f2bf(b) << 16);
        if (lane == 0) w2[u] = s;
    }
}

// GEMM v5: r3 pipeline (LDS-staged, verified) + sector-complete epilogue.
// 512 blocks x 256 thr (4 waves), 2 blocks/CU (64 KB LDS).
// Wave (wr=wv>>1, wc2=wv&1): rows wr*32 of each 64-row subtile, cols wc2*64
// (TWO adjacent 32-col MFMA tiles sharing one A fragment). The epilogue's two
// 128B stores per row are issued back-to-back by the SAME wave -> each 256B
// HBM sector is completed immediately (fix for r4's 1.49x write amplification).
__global__ __launch_bounds__(256, 2) void gemm_kernel(
    const unsigned short* __restrict__ xb, const unsigned short* __restrict__ wt,
    const float* __restrict__ x2, const float* __restrict__ w2,
    float* __restrict__ out)
{
    __shared__ __align__(16) unsigned short Bs[GBN * K_DIM];      // 32 KB, swizzled
    __shared__ __align__(16) unsigned short As[2][GBM * K_DIM];   // 2 x 16 KB, swizzled

    const int tid = threadIdx.x;
    const int wv = tid >> 6;
    const int lane = tid & 63;
    const int lc = lane & 31;
    const int hi = lane >> 5;
    const int wr = wv >> 1;                             // 0..1 row group (32 rows)
    const int wc2 = wv & 1;                             // 0..1 col pair (64 cols)

    // XCD-heuristic mapping (same as r3): b%8 -> contiguous 4096-row band.
    const int b = blockIdx.x;
    const int ut = (b >> 3) & 7;
    const int msb = (b & 7) * 8 + (b >> 6);
    const int u0 = ut * GBN;
    const int mbase = msb * (GBM * NMS);

    // ---- prologue DMA (linear LDS dest + inverse-swizzled global source) ----
    #pragma unroll
    for (int i = 0; i < 8; ++i) {                       // B: 32 KB
        const int p = i * 256 + tid;                    // physical 16B slot
        const int row = p >> 4;
        const int j = (p & 15) ^ (row & 15);
        async_load16(wt + ((size_t)(u0 + row) << 7) + j * 8,
                     &Bs[(i * 256 + (tid & 192)) * 8]);
    }
    #pragma unroll
    for (int i = 0; i < 4; ++i) {                       // A[0]: 16 KB
        const int p = i * 256 + tid;
        const int row = p >> 4;
        const int j = (p & 15) ^ (row & 15);
        async_load16(xb + ((size_t)(mbase + row) << 7) + j * 8,
                     &As[0][(i * 256 + (tid & 192)) * 8]);
    }

    const float w2v0 = w2[u0 + wc2 * 64 + lc];
    const float w2v1 = w2[u0 + wc2 * 64 + 32 + lc];

    __syncthreads();                                    // B + A[0] resident

    // ---- B fragments: two adjacent col tiles, 64 VGPR ----
    s16x8 bfr0[8], bfr1[8];
    #pragma unroll
    for (int st = 0; st < 8; ++st) {
        const int j0 = (st << 1) + hi;
        const int r0 = wc2 * 64 + lc;
        const int r1 = wc2 * 64 + 32 + lc;
        bfr0[st] = *(const s16x8*)&Bs[((r0 << 4) + (j0 ^ (r0 & 15))) * 8];
        bfr1[st] = *(const s16x8*)&Bs[((r1 << 4) + (j0 ^ (r1 & 15))) * 8];
    }

    #pragma unroll
    for (int ms = 0; ms < NMS; ++ms) {
        // issue next A-tile DMA first: flies under this subtile's compute+stores
        if (ms + 1 < NMS) {
            #pragma unroll
            for (int i = 0; i < 4; ++i) {
                const int p = i * 256 + tid;
                const int row = p >> 4;
                const int j = (p & 15) ^ (row & 15);
                async_load16(xb + ((size_t)(mbase + (ms + 1) * GBM + row) << 7) + j * 8,
                             &As[(ms + 1) & 1][(i * 256 + (tid & 192)) * 8]);
            }
        }

        const int mb = mbase + ms * GBM + wr * 32;
        const float x2row = x2[mb + lc];                // 128B broadcast load

        f32x16 acc0 = {}, acc1 = {};
        #pragma unroll
        for (int st = 0; st < 8; ++st) {
            const int row = wr * 32 + lc;
            const int j0 = (st << 1) + hi;
            const s16x8 af = *(const s16x8*)&As[ms & 1][((row << 4) + (j0 ^ (row & 15))) * 8];
            acc0 = __builtin_amdgcn_mfma_f32_32x32x16_bf16(af, bfr0[st], acc0, 0, 0, 0);
            acc1 = __builtin_amdgcn_mfma_f32_32x32x16_bf16(af, bfr1[st], acc1, 0, 0, 0);
        }

        // C/D 32x32: col=lane&31, row=(r&3)+8*(r>>2)+4*hi (m74/m101-verified;
        // epilogue row/shfl math identical to the r3/r4-passed kernels).
        float* op = out + (size_t)mb * U_TOT + u0 + wc2 * 64 + lc;
        #pragma unroll
        for (int r = 0; r < 16; ++r) {
            const int t = (r & 3) + ((r >> 2) << 3);
            const int tt = t + (hi << 2);
            const float xs = __shfl(x2row, tt + (lane & 32));
            op[(size_t)tt * U_TOT]      = xs + w2v0 - 2.0f * acc0[r];   // cols +0..31
            op[(size_t)tt * U_TOT + 32] = xs + w2v1 - 2.0f * acc1[r];   // cols +32..63
        }
        if (ms + 1 < NMS) __syncthreads();              // one drain+barrier per subtile
    }
}

// Fallback (no workspace): correct fp32 path, used only if ws_size is too small.
__global__ __launch_bounds__(256) void fallback_kernel(
    const float* __restrict__ x, const float* __restrict__ w,
    float* __restrict__ out)
{
    __shared__ float xrow[K_DIM];
    const int m = blockIdx.x;
    const int tid = threadIdx.x;
    if (tid < K_DIM) xrow[tid] = x[(size_t)m * K_DIM + tid];
    __syncthreads();
    float x2 = 0.f;
    #pragma unroll
    for (int k = 0; k < K_DIM; ++k) x2 += xrow[k] * xrow[k];
    #pragma unroll
    for (int uu = 0; uu < 4; ++uu) {
        const int u = uu * 256 + tid;
        float dot = 0.f, w2 = 0.f;
        for (int k = 0; k < K_DIM; ++k) {
            const float wv = w[(size_t)k * U_TOT + u];
            dot += xrow[k] * wv;
            w2 += wv * wv;
        }
        out[(size_t)m * U_TOT + u] = x2 + w2 - 2.0f * dot;
    }
}

extern "C" void kernel_launch(void* const* d_in, const int* in_sizes, int n_in,
                              void* d_out, int out_size, void* d_ws, size_t ws_size,
                              hipStream_t stream) {
    const float* x = (const float*)d_in[0];
    const float* w = (const float*)d_in[1];
    float* out = (float*)d_out;

    // ws layout: xb bf16[32768*128] | wt bf16[1024*128] | x2 f32[32768] | w2 f32[1024]
    const size_t need = (size_t)M_TOT * K_DIM * 2 + (size_t)U_TOT * K_DIM * 2
                      + (size_t)M_TOT * 4 + (size_t)U_TOT * 4;
    if (ws_size < need) {
        fallback_kernel<<<M_TOT, 256, 0, stream>>>(x, w, out);
        return;
    }

    unsigned short* xb = (unsigned short*)d_ws;
    unsigned short* wt = xb + (size_t)M_TOT * K_DIM;
    float* x2 = (float*)(wt + (size_t)U_TOT * K_DIM);
    float* w2 = x2 + M_TOT;

    prep_kernel<<<4096 + 256, 256, 0, stream>>>(x, w, (unsigned int*)xb,
                                                (unsigned int*)wt, x2, w2);
    gemm_kernel<<<(M_TOT / (GBM * NMS)) * (U_TOT / GBN), 256, 0, stream>>>(xb, wt, x2, w2, out);
}